// Round 2
// 436.857 us; speedup vs baseline: 1.0586x; 1.0586x over previous
//
#include <hip/hip_runtime.h>

typedef _Float16 f16;
typedef _Float16 half8 __attribute__((ext_vector_type(8)));
typedef _Float16 half4 __attribute__((ext_vector_type(4)));
typedef float floatx4 __attribute__((ext_vector_type(4)));

#define MFMA16(a, b, c) __builtin_amdgcn_mfma_f32_16x16x32_f16(a, b, c, 0, 0, 0)

union H8 { half8 v; f16 e[8]; };

// async global->LDS, 16B per lane; LDS side = wave-uniform base + lane*16
__device__ __forceinline__ void gload16(const void* g, void* l) {
    __builtin_amdgcn_global_load_lds((const __attribute__((address_space(1))) void*)g,
                                     (__attribute__((address_space(3))) void*)l, 16, 0, 0);
}

// ---------------------------------------------------------------------------
// Kernel 0: convert query [16.8M], W_in [262144], W_out [524288] fp32 -> fp16
// ---------------------------------------------------------------------------
__global__ __launch_bounds__(256) void k_cvt(const float* __restrict__ query,
                                             const float* __restrict__ Wi,
                                             const float* __restrict__ Wo,
                                             f16* __restrict__ q16,
                                             f16* __restrict__ W16)
{
    int i = blockIdx.x * 256 + threadIdx.x;   // float4 index, 4390912 total
    const float4* src;
    f16* dst;
    if (i < 4194304) { src = (const float4*)query + i; dst = q16 + (size_t)i * 4; }
    else if (i < 4259840) { int j = i - 4194304; src = (const float4*)Wi + j; dst = W16 + (size_t)j * 4; }
    else { int j = i - 4259840; src = (const float4*)Wo + j; dst = W16 + 262144 + (size_t)j * 4; }
    float4 v = *src;
    half4 h = {(f16)v.x, (f16)v.y, (f16)v.z, (f16)v.w};
    *reinterpret_cast<half4*>(dst) = h;
}

// ---------------------------------------------------------------------------
// Kernel 1: q = q16 @ W16^T (fp16 gl_lds GEMM, BK=64, 128x128 tile).
// 1D grid 1024 with XCD swizzle: the 4 n-blocks sharing one A-strip get ids
// congruent mod 8 -> same XCD -> A fetched into that L2 once.
// ---------------------------------------------------------------------------
__global__ __launch_bounds__(256) void k_qin(const f16* __restrict__ q16,
                                             const f16* __restrict__ W16,
                                             f16* __restrict__ comb,
                                             f16* __restrict__ qT)
{
    __shared__ char sm[34816];
    f16* At = (f16*)sm;            // 16 blocks x 512 halfs
    f16* Bt = (f16*)(sm + 16384);
    const int tid = threadIdx.x, lane = tid & 63, w = tid >> 6;
    const int l15 = lane & 15, quad = lane >> 4;
    const int id = blockIdx.x, xcd = id & 7, u = id >> 3;
    const int mbase = (xcd * 32 + (u >> 2)) * 128;   // m-tile 0..255
    const int nbase = (u & 3) * 128;                 // n-tile 0..3
    const int wm = (w & 1) * 64, wn = (w >> 1) * 64;
    const int ia = wm >> 4, jb = wn >> 4;

    floatx4 acc[4][4];
#pragma unroll
    for (int i = 0; i < 4; ++i)
#pragma unroll
        for (int j = 0; j < 4; ++j) acc[i][j] = (floatx4)0.f;

    for (int k0 = 0; k0 < 512; k0 += 64) {
        __syncthreads();
#pragma unroll
        for (int jr = 0; jr < 4; ++jr) {
            int bi = jr * 4 + w, i2 = bi >> 1, s = bi & 1;
            gload16(q16 + (size_t)(mbase + i2 * 16 + l15) * 512 + k0 + s * 32 + quad * 8, At + bi * 512);
            gload16(W16 + (size_t)(nbase + i2 * 16 + l15) * 512 + k0 + s * 32 + quad * 8, Bt + bi * 512);
        }
        __syncthreads();
#pragma unroll
        for (int s = 0; s < 2; ++s) {
            half8 a[4], bf[4];
#pragma unroll
            for (int i = 0; i < 4; ++i)
                a[i] = *reinterpret_cast<half8*>(At + ((ia + i) * 2 + s) * 512 + lane * 8);
#pragma unroll
            for (int j = 0; j < 4; ++j)
                bf[j] = *reinterpret_cast<half8*>(Bt + ((jb + j) * 2 + s) * 512 + lane * 8);
#pragma unroll
            for (int i = 0; i < 4; ++i)
#pragma unroll
                for (int j = 0; j < 4; ++j)
                    acc[i][j] = MFMA16(a[i], bf[j], acc[i][j]);
        }
    }
    const int bb = mbase >> 11, tb = mbase & 2047;
    f16* ct = (f16*)sm;   // phase A: row-major [128][136]
    __syncthreads();
#pragma unroll
    for (int i = 0; i < 4; ++i)
#pragma unroll
        for (int j = 0; j < 4; ++j)
#pragma unroll
            for (int r = 0; r < 4; ++r)
                ct[(wm + i * 16 + quad * 4 + r) * 136 + wn + j * 16 + l15] = (f16)acc[i][j][r];
    __syncthreads();
#pragma unroll
    for (int it = 0; it < 8; ++it) {
        int c = it * 256 + tid, r = c >> 4, c8 = (c & 15) << 3;
        *reinterpret_cast<half8*>(comb + (size_t)(mbase + r) * 1024 + 512 + nbase + c8) =
            *reinterpret_cast<half8*>(ct + r * 136 + c8);
    }
    __syncthreads();
    // phase B: column-major [128 cols][136] — vectorized half4 dumps from acc
#pragma unroll
    for (int i = 0; i < 4; ++i)
#pragma unroll
        for (int j = 0; j < 4; ++j) {
            half4 h = {(f16)acc[i][j][0], (f16)acc[i][j][1], (f16)acc[i][j][2], (f16)acc[i][j][3]};
            *reinterpret_cast<half4*>(ct + (wn + j * 16 + l15) * 136 + wm + i * 16 + quad * 4) = h;
        }
    __syncthreads();
    // qT writes: 16 lanes share a d-row -> 256 B contiguous global segments
#pragma unroll
    for (int it = 0; it < 8; ++it) {
        int c = it * 256 + tid, dd = c >> 4, tc = (c & 15) << 3;
        *reinterpret_cast<half8*>(qT + ((size_t)bb * 512 + nbase + dd) * 2048 + tb + tc) =
            *reinterpret_cast<half8*>(ct + dd * 136 + tc);
    }
}

// ---------------------------------------------------------------------------
// Kernel 2: S = q @ q^T, causal tiles only, fp32 packed output.
// grid = (136 tiles, ng batches). BK=64.
// ---------------------------------------------------------------------------
__global__ __launch_bounds__(256) void k_sgemm(const f16* __restrict__ comb,
                                               float* __restrict__ Sg, int batch0)
{
    __shared__ char sm[32768];
    f16* At = (f16*)sm;
    f16* Bt = (f16*)(sm + 16384);
    const int tid = threadIdx.x, lane = tid & 63, w = tid >> 6;
    const int l15 = lane & 15, quad = lane >> 4;
    const int wm = (w & 1) * 64, wn = (w >> 1) * 64;
    const int ia = wm >> 4, jb = wn >> 4;

    int bx = blockIdx.x, mt = 0;
    while ((mt + 1) * (mt + 2) / 2 <= bx) ++mt;
    const int nt = bx - mt * (mt + 1) / 2;
    const int b = batch0 + blockIdx.y;
    const f16* qa = comb + ((size_t)b * 2048 + mt * 128) * 1024 + 512;
    const f16* qb = comb + ((size_t)b * 2048 + nt * 128) * 1024 + 512;

    floatx4 acc[4][4];
#pragma unroll
    for (int i = 0; i < 4; ++i)
#pragma unroll
        for (int j = 0; j < 4; ++j) acc[i][j] = (floatx4)0.f;

    for (int k0 = 0; k0 < 512; k0 += 64) {
        __syncthreads();
#pragma unroll
        for (int jr = 0; jr < 4; ++jr) {
            int bi = jr * 4 + w, i2 = bi >> 1, s = bi & 1;
            gload16(qa + (size_t)(i2 * 16 + l15) * 1024 + k0 + s * 32 + quad * 8, At + bi * 512);
            gload16(qb + (size_t)(i2 * 16 + l15) * 1024 + k0 + s * 32 + quad * 8, Bt + bi * 512);
        }
        __syncthreads();
#pragma unroll
        for (int s = 0; s < 2; ++s) {
            half8 a[4], bf[4];
#pragma unroll
            for (int i = 0; i < 4; ++i)
                a[i] = *reinterpret_cast<half8*>(At + ((ia + i) * 2 + s) * 512 + lane * 8);
#pragma unroll
            for (int j = 0; j < 4; ++j)
                bf[j] = *reinterpret_cast<half8*>(Bt + ((jb + j) * 2 + s) * 512 + lane * 8);
#pragma unroll
            for (int i = 0; i < 4; ++i)
#pragma unroll
                for (int j = 0; j < 4; ++j)
                    acc[i][j] = MFMA16(a[i], bf[j], acc[i][j]);
        }
    }
    float* St = Sg + ((size_t)blockIdx.y * 136 + bx) * 16384;
#pragma unroll
    for (int i = 0; i < 4; ++i)
#pragma unroll
        for (int j = 0; j < 4; ++j)
#pragma unroll
            for (int r = 0; r < 4; ++r)
                St[(wm + i * 16 + quad * 4 + r) * 128 + wn + j * 16 + l15] = acc[i][j][r];
}

// ---------------------------------------------------------------------------
// Kernel 3: row softmax, IN-PLACE: reads fp32 S row, writes normalized fp16 P
// into the first half of the same row's storage. Each row is owned by exactly
// one wave (full row registered in sv[] before any store) -> no hazard.
// Single non-restrict pointer (S and P alias).
// ---------------------------------------------------------------------------
__global__ __launch_bounds__(256) void k_softmax(float* Sg)
{
    const int tid = threadIdx.x, lane = tid & 63, w = tid >> 6;
    const int row = blockIdx.x * 4 + w;
    const int gb = blockIdx.y;
    const int mt = row >> 7;
    const size_t tbase = ((size_t)gb * 136 + (size_t)(mt * (mt + 1)) / 2) * 16384;
    const int padlen = (mt + 1) * 128;
    const int r128 = (row & 127) * 128;
    f16* Ph = (f16*)Sg;

    float sv[32];
    float m = -1e38f;
#pragma unroll
    for (int it = 0; it < 32; ++it) {
        int c = it * 64 + lane;
        float p = -1e38f;
        if (c < row) {
            p = Sg[tbase + (size_t)(c >> 7) * 16384 + r128 + (c & 127)];
            m = fmaxf(m, p);
        }
        sv[it] = p;
    }
#pragma unroll
    for (int msk = 32; msk >= 1; msk >>= 1) m = fmaxf(m, __shfl_xor(m, msk));
    float l = 0.f;
#pragma unroll
    for (int it = 0; it < 32; ++it) {
        int c = it * 64 + lane;
        float p = 0.f;
        if (c < row) { p = __expf(sv[it] - m); l += p; }
        sv[it] = p;
    }
#pragma unroll
    for (int msk = 32; msk >= 1; msk >>= 1) l += __shfl_xor(l, msk);
    const float invl = (row > 0) ? 1.f / l : 0.f;
#pragma unroll
    for (int it = 0; it < 32; ++it) {
        int c = it * 64 + lane;
        if (c < padlen)
            Ph[2 * (tbase + (size_t)(c >> 7) * 16384 + r128) + (c & 127)] = (f16)(sv[it] * invl);
    }
}

// ---------------------------------------------------------------------------
// Kernel 4: mix = P @ q (B = qT), fp16 gl_lds GEMM, K = (mt+1)*128.
// P read in-place from the Sg region (fp16 rows at stride 256 halfs).
//
// v2: uniform-work pairing + 2-phase prefetch pipeline.
//  - Each block processes TWO output tiles: mt = p and mt = 15-p -> exactly
//    34 K-iterations per block. grid = 32*ng = 512 blocks -> 2 blocks/CU,
//    all co-resident from t=0, no straggler tail (old version: 2..32 iters
//    per block, avg occupancy 14.5% from the mt=15 tail).
//  - Decode p = id&7: the pair (p,15-p) pins to XCD p, and the 4 nb-blocks
//    of one (gb,p) share that XCD's L2 for the P strip (ids == p mod 8).
//  - Double-buffered LDS (2 x 32 KiB = 64 KiB static, the gfx950 per-WG
//    limit; fits 2 blocks/CU of the 160 KiB pool); next iteration's
//    global_load_lds issued BEFORE current MFMAs; ONE barrier per
//    iteration. Staging latency now overlaps compute.
//  - ct epilogue buffer aliases the (dead) staging buffers.
// ---------------------------------------------------------------------------
__global__ __launch_bounds__(256) void k_pv(const float* Sg,
                                            const f16* __restrict__ qT,
                                            f16* __restrict__ comb, int batch0)
{
    __shared__ char sm[65536];
    const int tid = threadIdx.x, lane = tid & 63, w = tid >> 6;
    const int l15 = lane & 15, quad = lane >> 4;
    const int wm = (w & 1) * 64, wn = (w >> 1) * 64;
    const int ia = wm >> 4, jb = wn >> 4;
    const int id = blockIdx.x;
    const int p = id & 7, nb = (id >> 3) & 3, gb = id >> 5;
    const int b = batch0 + gb;
    const f16* Ph = (const f16*)(Sg + (size_t)gb * 136 * 16384);
    const f16* qTb = qT + ((size_t)b * 512 + nb * 128) * 2048;

    for (int t = 0; t < 2; ++t) {
        const int mt = t ? (15 - p) : p;
        const int tb0 = mt * (mt + 1) / 2;
        const int kit = (mt + 1) * 2;

        floatx4 acc[4][4];
#pragma unroll
        for (int i = 0; i < 4; ++i)
#pragma unroll
            for (int j = 0; j < 4; ++j) acc[i][j] = (floatx4)0.f;

        // stage K-iter `it` into LDS buffer `bsel` (0/1)
        auto STAGE = [&](int it, int bsel) {
            f16* At = (f16*)(sm + bsel * 32768);
            f16* Bt = At + 8192;
            const int k0 = it * 64;
            const int tt = tb0 + (k0 >> 7), c0 = k0 & 64;
#pragma unroll
            for (int jr = 0; jr < 4; ++jr) {
                int bi = jr * 4 + w, i2 = bi >> 1, s = bi & 1;
                gload16(Ph + 2 * ((size_t)tt * 16384 + (size_t)(i2 * 16 + l15) * 128) + c0 + s * 32 + quad * 8,
                        At + bi * 512);
                gload16(qTb + (size_t)(i2 * 16 + l15) * 2048 + k0 + s * 32 + quad * 8, Bt + bi * 512);
            }
        };

        STAGE(0, 0);
        __syncthreads();   // drains vmcnt(0): buf0 ready
        for (int it = 0; it < kit; ++it) {
            const int cur = it & 1;
            if (it + 1 < kit) STAGE(it + 1, cur ^ 1);   // prefetch overlaps compute below
            f16* At = (f16*)(sm + cur * 32768);
            f16* Bt = At + 8192;
#pragma unroll
            for (int s = 0; s < 2; ++s) {
                half8 a[4], bf[4];
#pragma unroll
                for (int i = 0; i < 4; ++i)
                    a[i] = *reinterpret_cast<half8*>(At + ((ia + i) * 2 + s) * 512 + lane * 8);
#pragma unroll
                for (int j = 0; j < 4; ++j)
                    bf[j] = *reinterpret_cast<half8*>(Bt + ((jb + j) * 2 + s) * 512 + lane * 8);
#pragma unroll
                for (int i = 0; i < 4; ++i)
#pragma unroll
                    for (int j = 0; j < 4; ++j)
                        acc[i][j] = MFMA16(a[i], bf[j], acc[i][j]);
            }
            __syncthreads();   // staged loads drained + all waves done reading cur
        }

        // epilogue: ct aliases the staging buffers (all dead past last barrier)
        f16* ct = (f16*)sm;
#pragma unroll
        for (int i = 0; i < 4; ++i)
#pragma unroll
            for (int j = 0; j < 4; ++j)
#pragma unroll
                for (int r = 0; r < 4; ++r)
                    ct[(wm + i * 16 + quad * 4 + r) * 136 + wn + j * 16 + l15] = (f16)acc[i][j][r];
        __syncthreads();
#pragma unroll
        for (int it = 0; it < 8; ++it) {
            int c = it * 256 + tid, r = c >> 4, c8 = (c & 15) << 3;
            *reinterpret_cast<half8*>(comb + ((size_t)b * 2048 + mt * 128 + r) * 1024 + nb * 128 + c8) =
                *reinterpret_cast<half8*>(ct + r * 136 + c8);
        }
        __syncthreads();   // ct reads done before next tile re-stages over it
    }
}

// ---------------------------------------------------------------------------
// Kernel 5: out = comb @ W_out^T (fp16 gl_lds GEMM, fp32 out). K=1024.
// 1D grid 1024, XCD swizzle (4 n-blocks of one A-strip -> same XCD).
// ---------------------------------------------------------------------------
__global__ __launch_bounds__(256) void k_out(const f16* __restrict__ comb,
                                             const f16* __restrict__ Wo16,
                                             float* __restrict__ out)
{
    __shared__ char sm[32768];
    f16* At = (f16*)sm;
    f16* Bt = (f16*)(sm + 16384);
    const int tid = threadIdx.x, lane = tid & 63, w = tid >> 6;
    const int l15 = lane & 15, quad = lane >> 4;
    const int id = blockIdx.x, xcd = id & 7, u = id >> 3;
    const int mbase = (xcd * 32 + (u >> 2)) * 128;
    const int nbase = (u & 3) * 128;
    const int wm = (w & 1) * 64, wn = (w >> 1) * 64;
    const int ia = wm >> 4, jb = wn >> 4;

    floatx4 acc[4][4];
#pragma unroll
    for (int i = 0; i < 4; ++i)
#pragma unroll
        for (int j = 0; j < 4; ++j) acc[i][j] = (floatx4)0.f;

    for (int k0 = 0; k0 < 1024; k0 += 64) {
        __syncthreads();
#pragma unroll
        for (int jr = 0; jr < 4; ++jr) {
            int bi = jr * 4 + w, i2 = bi >> 1, s = bi & 1;
            gload16(comb + (size_t)(mbase + i2 * 16 + l15) * 1024 + k0 + s * 32 + quad * 8,
                    At + bi * 512);
            gload16(Wo16 + (size_t)(nbase + i2 * 16 + l15) * 1024 + k0 + s * 32 + quad * 8,
                    Bt + bi * 512);
        }
        __syncthreads();
#pragma unroll
        for (int s = 0; s < 2; ++s) {
            half8 a[4], bf[4];
#pragma unroll
            for (int i = 0; i < 4; ++i)
                a[i] = *reinterpret_cast<half8*>(At + ((ia + i) * 2 + s) * 512 + lane * 8);
#pragma unroll
            for (int j = 0; j < 4; ++j)
                bf[j] = *reinterpret_cast<half8*>(Bt + ((jb + j) * 2 + s) * 512 + lane * 8);
#pragma unroll
            for (int i = 0; i < 4; ++i)
#pragma unroll
                for (int j = 0; j < 4; ++j)
                    acc[i][j] = MFMA16(a[i], bf[j], acc[i][j]);
        }
    }
#pragma unroll
    for (int i = 0; i < 4; ++i)
#pragma unroll
        for (int j = 0; j < 4; ++j)
#pragma unroll
            for (int r = 0; r < 4; ++r)
                out[(size_t)(mbase + wm + i * 16 + quad * 4 + r) * 512 + nbase + wn + j * 16 + l15] =
                    acc[i][j][r];
}

extern "C" void kernel_launch(void* const* d_in, const int* in_sizes, int n_in,
                              void* d_out, int out_size, void* d_ws, size_t ws_size,
                              hipStream_t stream)
{
    const float* query = (const float*)d_in[0];
    const float* W_in  = (const float*)d_in[1];
    const float* W_out = (const float*)d_in[2];
    float* out = (float*)d_out;

    // ws layout (bytes):
    //   comb fp16 [32768][1024] (mix|q)        @ 0           (67,108,864)
    //   qT   fp16 [16][512][2048]              @ 67,108,864  (33,554,432)
    //   W16  fp16 [Wi 262144 | Wo 524288]      @ 100,663,296 (1,572,864)
    //   X    @ 102,236,160:
    //     q16 fp16 [16*2048*512] (33,554,432)  -- dead after k_qin
    //     Sg fp32 [ng*136*128*128] (aliases q16; P fp16 written in-place)
    const size_t XOFF = 102236160ull;
    f16* comb = (f16*)d_ws;
    f16* qT   = comb + (size_t)32768 * 1024;
    f16* W16  = qT + (size_t)16 * 512 * 2048;
    f16* q16  = (f16*)((char*)d_ws + XOFF);
    const size_t sgb = 136ull * 16384 * 4;   // per-batch Sg bytes (fp32)
    int ng;
    if (ws_size >= XOFF + 16 * sgb)      ng = 16;
    else if (ws_size >= XOFF + 8 * sgb)  ng = 8;
    else                                 ng = 4;
    float* Sg = (float*)((char*)d_ws + XOFF);

    k_cvt<<<17152, 256, 0, stream>>>(query, W_in, W_out, q16, W16);
    k_qin<<<1024, 256, 0, stream>>>(q16, W16, comb, qT);
    for (int g = 0; g < 16 / ng; ++g) {
        k_sgemm<<<dim3(136, ng), 256, 0, stream>>>(comb, Sg, g * ng);
        k_softmax<<<dim3(512, ng), 256, 0, stream>>>(Sg);
        k_pv<<<32 * ng, 256, 0, stream>>>(Sg, qT, comb, g * ng);
    }
    k_out<<<1024, 256, 0, stream>>>(comb, W16 + 262144, out);
}

// Round 3
// 432.040 us; speedup vs baseline: 1.0704x; 1.0111x over previous
//
#include <hip/hip_runtime.h>

typedef _Float16 f16;
typedef _Float16 half8 __attribute__((ext_vector_type(8)));
typedef _Float16 half4 __attribute__((ext_vector_type(4)));
typedef float floatx4 __attribute__((ext_vector_type(4)));

#define MFMA16(a, b, c) __builtin_amdgcn_mfma_f32_16x16x32_f16(a, b, c, 0, 0, 0)

union H8 { half8 v; f16 e[8]; };

// async global->LDS, 16B per lane; LDS side = wave-uniform base + lane*16
__device__ __forceinline__ void gload16(const void* g, void* l) {
    __builtin_amdgcn_global_load_lds((const __attribute__((address_space(1))) void*)g,
                                     (__attribute__((address_space(3))) void*)l, 16, 0, 0);
}

// ---------------------------------------------------------------------------
// Kernel 0: convert query [16.8M], W_in [262144], W_out [524288] fp32 -> fp16
// ---------------------------------------------------------------------------
__global__ __launch_bounds__(256) void k_cvt(const float* __restrict__ query,
                                             const float* __restrict__ Wi,
                                             const float* __restrict__ Wo,
                                             f16* __restrict__ q16,
                                             f16* __restrict__ W16)
{
    int i = blockIdx.x * 256 + threadIdx.x;   // float4 index, 4390912 total
    const float4* src;
    f16* dst;
    if (i < 4194304) { src = (const float4*)query + i; dst = q16 + (size_t)i * 4; }
    else if (i < 4259840) { int j = i - 4194304; src = (const float4*)Wi + j; dst = W16 + (size_t)j * 4; }
    else { int j = i - 4259840; src = (const float4*)Wo + j; dst = W16 + 262144 + (size_t)j * 4; }
    float4 v = *src;
    half4 h = {(f16)v.x, (f16)v.y, (f16)v.z, (f16)v.w};
    *reinterpret_cast<half4*>(dst) = h;
}

// ---------------------------------------------------------------------------
// Kernel 1: q = q16 @ W16^T (fp16 gl_lds GEMM, BK=64, 128x128 tile).
// 1D grid 1024 with XCD swizzle. v3: double-buffered 1-barrier K-loop
// (prefetch issued before MFMAs; __syncthreads drains vmcnt).
// ---------------------------------------------------------------------------
__global__ __launch_bounds__(256) void k_qin(const f16* __restrict__ q16,
                                             const f16* __restrict__ W16,
                                             f16* __restrict__ comb,
                                             f16* __restrict__ qT)
{
    __shared__ char sm[65536];
    const int tid = threadIdx.x, lane = tid & 63, w = tid >> 6;
    const int l15 = lane & 15, quad = lane >> 4;
    const int id = blockIdx.x, xcd = id & 7, u = id >> 3;
    const int mbase = (xcd * 32 + (u >> 2)) * 128;   // m-tile 0..255
    const int nbase = (u & 3) * 128;                 // n-tile 0..3
    const int wm = (w & 1) * 64, wn = (w >> 1) * 64;
    const int ia = wm >> 4, jb = wn >> 4;

    floatx4 acc[4][4];
#pragma unroll
    for (int i = 0; i < 4; ++i)
#pragma unroll
        for (int j = 0; j < 4; ++j) acc[i][j] = (floatx4)0.f;

    auto STAGE = [&](int k0, int bsel) {
        f16* At = (f16*)(sm + bsel * 32768);
        f16* Bt = At + 8192;
#pragma unroll
        for (int jr = 0; jr < 4; ++jr) {
            int bi = jr * 4 + w, i2 = bi >> 1, s = bi & 1;
            gload16(q16 + (size_t)(mbase + i2 * 16 + l15) * 512 + k0 + s * 32 + quad * 8, At + bi * 512);
            gload16(W16 + (size_t)(nbase + i2 * 16 + l15) * 512 + k0 + s * 32 + quad * 8, Bt + bi * 512);
        }
    };

    STAGE(0, 0);
    __syncthreads();   // buf0 ready
    for (int it = 0; it < 8; ++it) {
        const int cur = it & 1;
        if (it < 7) STAGE((it + 1) * 64, cur ^ 1);   // prefetch overlaps MFMAs
        f16* At = (f16*)(sm + cur * 32768);
        f16* Bt = At + 8192;
#pragma unroll
        for (int s = 0; s < 2; ++s) {
            half8 a[4], bf[4];
#pragma unroll
            for (int i = 0; i < 4; ++i)
                a[i] = *reinterpret_cast<half8*>(At + ((ia + i) * 2 + s) * 512 + lane * 8);
#pragma unroll
            for (int j = 0; j < 4; ++j)
                bf[j] = *reinterpret_cast<half8*>(Bt + ((jb + j) * 2 + s) * 512 + lane * 8);
#pragma unroll
            for (int i = 0; i < 4; ++i)
#pragma unroll
                for (int j = 0; j < 4; ++j)
                    acc[i][j] = MFMA16(a[i], bf[j], acc[i][j]);
        }
        __syncthreads();   // prefetch drained + all waves done with cur
    }
    const int bb = mbase >> 11, tb = mbase & 2047;
    f16* ct = (f16*)sm;   // phase A: row-major [128][136] (aliases dead staging bufs)
#pragma unroll
    for (int i = 0; i < 4; ++i)
#pragma unroll
        for (int j = 0; j < 4; ++j)
#pragma unroll
            for (int r = 0; r < 4; ++r)
                ct[(wm + i * 16 + quad * 4 + r) * 136 + wn + j * 16 + l15] = (f16)acc[i][j][r];
    __syncthreads();
#pragma unroll
    for (int it = 0; it < 8; ++it) {
        int c = it * 256 + tid, r = c >> 4, c8 = (c & 15) << 3;
        *reinterpret_cast<half8*>(comb + (size_t)(mbase + r) * 1024 + 512 + nbase + c8) =
            *reinterpret_cast<half8*>(ct + r * 136 + c8);
    }
    __syncthreads();
    // phase B: column-major [128 cols][136] — vectorized half4 dumps from acc
#pragma unroll
    for (int i = 0; i < 4; ++i)
#pragma unroll
        for (int j = 0; j < 4; ++j) {
            half4 h = {(f16)acc[i][j][0], (f16)acc[i][j][1], (f16)acc[i][j][2], (f16)acc[i][j][3]};
            *reinterpret_cast<half4*>(ct + (wn + j * 16 + l15) * 136 + wm + i * 16 + quad * 4) = h;
        }
    __syncthreads();
    // qT writes: 16 lanes share a d-row -> 256 B contiguous global segments
#pragma unroll
    for (int it = 0; it < 8; ++it) {
        int c = it * 256 + tid, dd = c >> 4, tc = (c & 15) << 3;
        *reinterpret_cast<half8*>(qT + ((size_t)bb * 512 + nbase + dd) * 2048 + tb + tc) =
            *reinterpret_cast<half8*>(ct + dd * 136 + tc);
    }
}

// ---------------------------------------------------------------------------
// Kernel 2: S = q @ q^T, causal tiles only, fp32 packed output.
// grid = (136 tiles, ng batches). BK=64.
// v3: double-buffered 1-barrier K-loop (same structure proven on k_pv:
// dur 104 -> off the top-5). Uniform 8 K-iters per block, no tail.
// ---------------------------------------------------------------------------
__global__ __launch_bounds__(256) void k_sgemm(const f16* __restrict__ comb,
                                               float* __restrict__ Sg, int batch0)
{
    __shared__ char sm[65536];
    const int tid = threadIdx.x, lane = tid & 63, w = tid >> 6;
    const int l15 = lane & 15, quad = lane >> 4;
    const int wm = (w & 1) * 64, wn = (w >> 1) * 64;
    const int ia = wm >> 4, jb = wn >> 4;

    int bx = blockIdx.x, mt = 0;
    while ((mt + 1) * (mt + 2) / 2 <= bx) ++mt;
    const int nt = bx - mt * (mt + 1) / 2;
    const int b = batch0 + blockIdx.y;
    const f16* qa = comb + ((size_t)b * 2048 + mt * 128) * 1024 + 512;
    const f16* qb = comb + ((size_t)b * 2048 + nt * 128) * 1024 + 512;

    floatx4 acc[4][4];
#pragma unroll
    for (int i = 0; i < 4; ++i)
#pragma unroll
        for (int j = 0; j < 4; ++j) acc[i][j] = (floatx4)0.f;

    auto STAGE = [&](int k0, int bsel) {
        f16* At = (f16*)(sm + bsel * 32768);
        f16* Bt = At + 8192;
#pragma unroll
        for (int jr = 0; jr < 4; ++jr) {
            int bi = jr * 4 + w, i2 = bi >> 1, s = bi & 1;
            gload16(qa + (size_t)(i2 * 16 + l15) * 1024 + k0 + s * 32 + quad * 8, At + bi * 512);
            gload16(qb + (size_t)(i2 * 16 + l15) * 1024 + k0 + s * 32 + quad * 8, Bt + bi * 512);
        }
    };

    STAGE(0, 0);
    __syncthreads();
    for (int it = 0; it < 8; ++it) {
        const int cur = it & 1;
        if (it < 7) STAGE((it + 1) * 64, cur ^ 1);
        f16* At = (f16*)(sm + cur * 32768);
        f16* Bt = At + 8192;
#pragma unroll
        for (int s = 0; s < 2; ++s) {
            half8 a[4], bf[4];
#pragma unroll
            for (int i = 0; i < 4; ++i)
                a[i] = *reinterpret_cast<half8*>(At + ((ia + i) * 2 + s) * 512 + lane * 8);
#pragma unroll
            for (int j = 0; j < 4; ++j)
                bf[j] = *reinterpret_cast<half8*>(Bt + ((jb + j) * 2 + s) * 512 + lane * 8);
#pragma unroll
            for (int i = 0; i < 4; ++i)
#pragma unroll
                for (int j = 0; j < 4; ++j)
                    acc[i][j] = MFMA16(a[i], bf[j], acc[i][j]);
        }
        __syncthreads();
    }
    float* St = Sg + ((size_t)blockIdx.y * 136 + bx) * 16384;
#pragma unroll
    for (int i = 0; i < 4; ++i)
#pragma unroll
        for (int j = 0; j < 4; ++j)
#pragma unroll
            for (int r = 0; r < 4; ++r)
                St[(wm + i * 16 + quad * 4 + r) * 128 + wn + j * 16 + l15] = acc[i][j][r];
}

// ---------------------------------------------------------------------------
// Kernel 3: row softmax, IN-PLACE: reads fp32 S row, writes normalized fp16 P
// into the first half of the same row's storage. Each row is owned by exactly
// one wave (full row registered in sv[] before any store) -> no hazard.
// Single non-restrict pointer (S and P alias).
// ---------------------------------------------------------------------------
__global__ __launch_bounds__(256) void k_softmax(float* Sg)
{
    const int tid = threadIdx.x, lane = tid & 63, w = tid >> 6;
    const int row = blockIdx.x * 4 + w;
    const int gb = blockIdx.y;
    const int mt = row >> 7;
    const size_t tbase = ((size_t)gb * 136 + (size_t)(mt * (mt + 1)) / 2) * 16384;
    const int padlen = (mt + 1) * 128;
    const int r128 = (row & 127) * 128;
    f16* Ph = (f16*)Sg;

    float sv[32];
    float m = -1e38f;
#pragma unroll
    for (int it = 0; it < 32; ++it) {
        int c = it * 64 + lane;
        float p = -1e38f;
        if (c < row) {
            p = Sg[tbase + (size_t)(c >> 7) * 16384 + r128 + (c & 127)];
            m = fmaxf(m, p);
        }
        sv[it] = p;
    }
#pragma unroll
    for (int msk = 32; msk >= 1; msk >>= 1) m = fmaxf(m, __shfl_xor(m, msk));
    float l = 0.f;
#pragma unroll
    for (int it = 0; it < 32; ++it) {
        int c = it * 64 + lane;
        float p = 0.f;
        if (c < row) { p = __expf(sv[it] - m); l += p; }
        sv[it] = p;
    }
#pragma unroll
    for (int msk = 32; msk >= 1; msk >>= 1) l += __shfl_xor(l, msk);
    const float invl = (row > 0) ? 1.f / l : 0.f;
#pragma unroll
    for (int it = 0; it < 32; ++it) {
        int c = it * 64 + lane;
        if (c < padlen)
            Ph[2 * (tbase + (size_t)(c >> 7) * 16384 + r128) + (c & 127)] = (f16)(sv[it] * invl);
    }
}

// ---------------------------------------------------------------------------
// Kernel 4: mix = P @ q (B = qT), fp16 gl_lds GEMM, K = (mt+1)*128.
// P read in-place from the Sg region (fp16 rows at stride 256 halfs).
// Uniform-work pairing (mt=p with 15-p: 34 K-iters/block, 512 blocks) +
// double-buffered 1-barrier pipeline. XCD-pinned via p = id&7.
// ---------------------------------------------------------------------------
__global__ __launch_bounds__(256) void k_pv(const float* Sg,
                                            const f16* __restrict__ qT,
                                            f16* __restrict__ comb, int batch0)
{
    __shared__ char sm[65536];
    const int tid = threadIdx.x, lane = tid & 63, w = tid >> 6;
    const int l15 = lane & 15, quad = lane >> 4;
    const int wm = (w & 1) * 64, wn = (w >> 1) * 64;
    const int ia = wm >> 4, jb = wn >> 4;
    const int id = blockIdx.x;
    const int p = id & 7, nb = (id >> 3) & 3, gb = id >> 5;
    const int b = batch0 + gb;
    const f16* Ph = (const f16*)(Sg + (size_t)gb * 136 * 16384);
    const f16* qTb = qT + ((size_t)b * 512 + nb * 128) * 2048;

    for (int t = 0; t < 2; ++t) {
        const int mt = t ? (15 - p) : p;
        const int tb0 = mt * (mt + 1) / 2;
        const int kit = (mt + 1) * 2;

        floatx4 acc[4][4];
#pragma unroll
        for (int i = 0; i < 4; ++i)
#pragma unroll
            for (int j = 0; j < 4; ++j) acc[i][j] = (floatx4)0.f;

        auto STAGE = [&](int it, int bsel) {
            f16* At = (f16*)(sm + bsel * 32768);
            f16* Bt = At + 8192;
            const int k0 = it * 64;
            const int tt = tb0 + (k0 >> 7), c0 = k0 & 64;
#pragma unroll
            for (int jr = 0; jr < 4; ++jr) {
                int bi = jr * 4 + w, i2 = bi >> 1, s = bi & 1;
                gload16(Ph + 2 * ((size_t)tt * 16384 + (size_t)(i2 * 16 + l15) * 128) + c0 + s * 32 + quad * 8,
                        At + bi * 512);
                gload16(qTb + (size_t)(i2 * 16 + l15) * 2048 + k0 + s * 32 + quad * 8, Bt + bi * 512);
            }
        };

        STAGE(0, 0);
        __syncthreads();   // buf0 ready
        for (int it = 0; it < kit; ++it) {
            const int cur = it & 1;
            if (it + 1 < kit) STAGE(it + 1, cur ^ 1);   // prefetch overlaps compute
            f16* At = (f16*)(sm + cur * 32768);
            f16* Bt = At + 8192;
#pragma unroll
            for (int s = 0; s < 2; ++s) {
                half8 a[4], bf[4];
#pragma unroll
                for (int i = 0; i < 4; ++i)
                    a[i] = *reinterpret_cast<half8*>(At + ((ia + i) * 2 + s) * 512 + lane * 8);
#pragma unroll
                for (int j = 0; j < 4; ++j)
                    bf[j] = *reinterpret_cast<half8*>(Bt + ((jb + j) * 2 + s) * 512 + lane * 8);
#pragma unroll
                for (int i = 0; i < 4; ++i)
#pragma unroll
                    for (int j = 0; j < 4; ++j)
                        acc[i][j] = MFMA16(a[i], bf[j], acc[i][j]);
            }
            __syncthreads();
        }

        // epilogue: ct aliases the staging buffers (all dead past last barrier)
        f16* ct = (f16*)sm;
#pragma unroll
        for (int i = 0; i < 4; ++i)
#pragma unroll
            for (int j = 0; j < 4; ++j)
#pragma unroll
                for (int r = 0; r < 4; ++r)
                    ct[(wm + i * 16 + quad * 4 + r) * 136 + wn + j * 16 + l15] = (f16)acc[i][j][r];
        __syncthreads();
#pragma unroll
        for (int it = 0; it < 8; ++it) {
            int c = it * 256 + tid, r = c >> 4, c8 = (c & 15) << 3;
            *reinterpret_cast<half8*>(comb + ((size_t)b * 2048 + mt * 128 + r) * 1024 + nb * 128 + c8) =
                *reinterpret_cast<half8*>(ct + r * 136 + c8);
        }
        __syncthreads();   // ct reads done before next tile re-stages over it
    }
}

// ---------------------------------------------------------------------------
// Kernel 5: out = comb @ W_out^T (fp16 gl_lds GEMM, fp32 out). K=1024.
// 1D grid 1024, XCD swizzle. v3: double-buffered 1-barrier K-loop.
// ---------------------------------------------------------------------------
__global__ __launch_bounds__(256) void k_out(const f16* __restrict__ comb,
                                             const f16* __restrict__ Wo16,
                                             float* __restrict__ out)
{
    __shared__ char sm[65536];
    const int tid = threadIdx.x, lane = tid & 63, w = tid >> 6;
    const int l15 = lane & 15, quad = lane >> 4;
    const int id = blockIdx.x, xcd = id & 7, u = id >> 3;
    const int mbase = (xcd * 32 + (u >> 2)) * 128;
    const int nbase = (u & 3) * 128;
    const int wm = (w & 1) * 64, wn = (w >> 1) * 64;
    const int ia = wm >> 4, jb = wn >> 4;

    floatx4 acc[4][4];
#pragma unroll
    for (int i = 0; i < 4; ++i)
#pragma unroll
        for (int j = 0; j < 4; ++j) acc[i][j] = (floatx4)0.f;

    auto STAGE = [&](int k0, int bsel) {
        f16* At = (f16*)(sm + bsel * 32768);
        f16* Bt = At + 8192;
#pragma unroll
        for (int jr = 0; jr < 4; ++jr) {
            int bi = jr * 4 + w, i2 = bi >> 1, s = bi & 1;
            gload16(comb + (size_t)(mbase + i2 * 16 + l15) * 1024 + k0 + s * 32 + quad * 8,
                    At + bi * 512);
            gload16(Wo16 + (size_t)(nbase + i2 * 16 + l15) * 1024 + k0 + s * 32 + quad * 8,
                    Bt + bi * 512);
        }
    };

    STAGE(0, 0);
    __syncthreads();
    for (int it = 0; it < 16; ++it) {
        const int cur = it & 1;
        if (it < 15) STAGE((it + 1) * 64, cur ^ 1);
        f16* At = (f16*)(sm + cur * 32768);
        f16* Bt = At + 8192;
#pragma unroll
        for (int s = 0; s < 2; ++s) {
            half8 a[4], bf[4];
#pragma unroll
            for (int i = 0; i < 4; ++i)
                a[i] = *reinterpret_cast<half8*>(At + ((ia + i) * 2 + s) * 512 + lane * 8);
#pragma unroll
            for (int j = 0; j < 4; ++j)
                bf[j] = *reinterpret_cast<half8*>(Bt + ((jb + j) * 2 + s) * 512 + lane * 8);
#pragma unroll
            for (int i = 0; i < 4; ++i)
#pragma unroll
                for (int j = 0; j < 4; ++j)
                    acc[i][j] = MFMA16(a[i], bf[j], acc[i][j]);
        }
        __syncthreads();
    }
#pragma unroll
    for (int i = 0; i < 4; ++i)
#pragma unroll
        for (int j = 0; j < 4; ++j)
#pragma unroll
            for (int r = 0; r < 4; ++r)
                out[(size_t)(mbase + wm + i * 16 + quad * 4 + r) * 512 + nbase + wn + j * 16 + l15] =
                    acc[i][j][r];
}

extern "C" void kernel_launch(void* const* d_in, const int* in_sizes, int n_in,
                              void* d_out, int out_size, void* d_ws, size_t ws_size,
                              hipStream_t stream)
{
    const float* query = (const float*)d_in[0];
    const float* W_in  = (const float*)d_in[1];
    const float* W_out = (const float*)d_in[2];
    float* out = (float*)d_out;

    // ws layout (bytes):
    //   comb fp16 [32768][1024] (mix|q)        @ 0           (67,108,864)
    //   qT   fp16 [16][512][2048]              @ 67,108,864  (33,554,432)
    //   W16  fp16 [Wi 262144 | Wo 524288]      @ 100,663,296 (1,572,864)
    //   X    @ 102,236,160:
    //     q16 fp16 [16*2048*512] (33,554,432)  -- dead after k_qin
    //     Sg fp32 [ng*136*128*128] (aliases q16; P fp16 written in-place)
    const size_t XOFF = 102236160ull;
    f16* comb = (f16*)d_ws;
    f16* qT   = comb + (size_t)32768 * 1024;
    f16* W16  = qT + (size_t)16 * 512 * 2048;
    f16* q16  = (f16*)((char*)d_ws + XOFF);
    const size_t sgb = 136ull * 16384 * 4;   // per-batch Sg bytes (fp32)
    int ng;
    if (ws_size >= XOFF + 16 * sgb)      ng = 16;
    else if (ws_size >= XOFF + 8 * sgb)  ng = 8;
    else                                 ng = 4;
    float* Sg = (float*)((char*)d_ws + XOFF);

    k_cvt<<<17152, 256, 0, stream>>>(query, W_in, W_out, q16, W16);
    k_qin<<<1024, 256, 0, stream>>>(q16, W16, comb, qT);
    for (int g = 0; g < 16 / ng; ++g) {
        k_sgemm<<<dim3(136, ng), 256, 0, stream>>>(comb, Sg, g * ng);
        k_softmax<<<dim3(512, ng), 256, 0, stream>>>(Sg);
        k_pv<<<32 * ng, 256, 0, stream>>>(Sg, qT, comb, g * ng);
    }
    k_out<<<1024, 256, 0, stream>>>(comb, W16 + 262144, out);
}

// Round 4
// 428.556 us; speedup vs baseline: 1.0791x; 1.0081x over previous
//
#include <hip/hip_runtime.h>

typedef _Float16 f16;
typedef _Float16 half8 __attribute__((ext_vector_type(8)));
typedef _Float16 half4 __attribute__((ext_vector_type(4)));
typedef float floatx4 __attribute__((ext_vector_type(4)));

#define MFMA16(a, b, c) __builtin_amdgcn_mfma_f32_16x16x32_f16(a, b, c, 0, 0, 0)

union H8 { half8 v; f16 e[8]; };

// async global->LDS, 16B per lane; LDS side = wave-uniform base + lane*16
__device__ __forceinline__ void gload16(const void* g, void* l) {
    __builtin_amdgcn_global_load_lds((const __attribute__((address_space(1))) void*)g,
                                     (__attribute__((address_space(3))) void*)l, 16, 0, 0);
}

// ---------------------------------------------------------------------------
// Kernel 0: convert query [16.8M], W_in [262144], W_out [524288] fp32 -> fp16
// ---------------------------------------------------------------------------
__global__ __launch_bounds__(256) void k_cvt(const float* __restrict__ query,
                                             const float* __restrict__ Wi,
                                             const float* __restrict__ Wo,
                                             f16* __restrict__ q16,
                                             f16* __restrict__ W16)
{
    int i = blockIdx.x * 256 + threadIdx.x;   // float4 index, 4390912 total
    const float4* src;
    f16* dst;
    if (i < 4194304) { src = (const float4*)query + i; dst = q16 + (size_t)i * 4; }
    else if (i < 4259840) { int j = i - 4194304; src = (const float4*)Wi + j; dst = W16 + (size_t)j * 4; }
    else { int j = i - 4259840; src = (const float4*)Wo + j; dst = W16 + 262144 + (size_t)j * 4; }
    float4 v = *src;
    half4 h = {(f16)v.x, (f16)v.y, (f16)v.z, (f16)v.w};
    *reinterpret_cast<half4*>(dst) = h;
}

// ---------------------------------------------------------------------------
// Kernel 1: q = q16 @ W16^T (fp16 gl_lds GEMM, BK=64, 128x128 tile).
// 1D grid 1024 with XCD swizzle. Double-buffered 1-barrier K-loop.
// ---------------------------------------------------------------------------
__global__ __launch_bounds__(256) void k_qin(const f16* __restrict__ q16,
                                             const f16* __restrict__ W16,
                                             f16* __restrict__ comb,
                                             f16* __restrict__ qT)
{
    __shared__ char sm[65536];
    const int tid = threadIdx.x, lane = tid & 63, w = tid >> 6;
    const int l15 = lane & 15, quad = lane >> 4;
    const int id = blockIdx.x, xcd = id & 7, u = id >> 3;
    const int mbase = (xcd * 32 + (u >> 2)) * 128;   // m-tile 0..255
    const int nbase = (u & 3) * 128;                 // n-tile 0..3
    const int wm = (w & 1) * 64, wn = (w >> 1) * 64;
    const int ia = wm >> 4, jb = wn >> 4;

    floatx4 acc[4][4];
#pragma unroll
    for (int i = 0; i < 4; ++i)
#pragma unroll
        for (int j = 0; j < 4; ++j) acc[i][j] = (floatx4)0.f;

    auto STAGE = [&](int k0, int bsel) {
        f16* At = (f16*)(sm + bsel * 32768);
        f16* Bt = At + 8192;
#pragma unroll
        for (int jr = 0; jr < 4; ++jr) {
            int bi = jr * 4 + w, i2 = bi >> 1, s = bi & 1;
            gload16(q16 + (size_t)(mbase + i2 * 16 + l15) * 512 + k0 + s * 32 + quad * 8, At + bi * 512);
            gload16(W16 + (size_t)(nbase + i2 * 16 + l15) * 512 + k0 + s * 32 + quad * 8, Bt + bi * 512);
        }
    };

    STAGE(0, 0);
    __syncthreads();   // buf0 ready
    for (int it = 0; it < 8; ++it) {
        const int cur = it & 1;
        if (it < 7) STAGE((it + 1) * 64, cur ^ 1);   // prefetch overlaps MFMAs
        f16* At = (f16*)(sm + cur * 32768);
        f16* Bt = At + 8192;
#pragma unroll
        for (int s = 0; s < 2; ++s) {
            half8 a[4], bf[4];
#pragma unroll
            for (int i = 0; i < 4; ++i)
                a[i] = *reinterpret_cast<half8*>(At + ((ia + i) * 2 + s) * 512 + lane * 8);
#pragma unroll
            for (int j = 0; j < 4; ++j)
                bf[j] = *reinterpret_cast<half8*>(Bt + ((jb + j) * 2 + s) * 512 + lane * 8);
#pragma unroll
            for (int i = 0; i < 4; ++i)
#pragma unroll
                for (int j = 0; j < 4; ++j)
                    acc[i][j] = MFMA16(a[i], bf[j], acc[i][j]);
        }
        __syncthreads();   // prefetch drained + all waves done with cur
    }
    const int bb = mbase >> 11, tb = mbase & 2047;
    f16* ct = (f16*)sm;   // phase A: row-major [128][136] (aliases dead staging bufs)
#pragma unroll
    for (int i = 0; i < 4; ++i)
#pragma unroll
        for (int j = 0; j < 4; ++j)
#pragma unroll
            for (int r = 0; r < 4; ++r)
                ct[(wm + i * 16 + quad * 4 + r) * 136 + wn + j * 16 + l15] = (f16)acc[i][j][r];
    __syncthreads();
#pragma unroll
    for (int it = 0; it < 8; ++it) {
        int c = it * 256 + tid, r = c >> 4, c8 = (c & 15) << 3;
        *reinterpret_cast<half8*>(comb + (size_t)(mbase + r) * 1024 + 512 + nbase + c8) =
            *reinterpret_cast<half8*>(ct + r * 136 + c8);
    }
    __syncthreads();
    // phase B: column-major [128 cols][136] — vectorized half4 dumps from acc
#pragma unroll
    for (int i = 0; i < 4; ++i)
#pragma unroll
        for (int j = 0; j < 4; ++j) {
            half4 h = {(f16)acc[i][j][0], (f16)acc[i][j][1], (f16)acc[i][j][2], (f16)acc[i][j][3]};
            *reinterpret_cast<half4*>(ct + (wn + j * 16 + l15) * 136 + wm + i * 16 + quad * 4) = h;
        }
    __syncthreads();
    // qT writes: 16 lanes share a d-row -> 256 B contiguous global segments
#pragma unroll
    for (int it = 0; it < 8; ++it) {
        int c = it * 256 + tid, dd = c >> 4, tc = (c & 15) << 3;
        *reinterpret_cast<half8*>(qT + ((size_t)bb * 512 + nbase + dd) * 2048 + tb + tc) =
            *reinterpret_cast<half8*>(ct + dd * 136 + tc);
    }
}

// ---------------------------------------------------------------------------
// Kernel 2: S = q @ q^T, causal tiles only, fp32 packed output.
// grid = (136 tiles, ng batches). BK=64. Double-buffered 1-barrier K-loop.
// v4: FULL-LINE output stores. Old epilogue scattered 4B stores (64B
// segments at 512B stride) -> every 128B line of Sg was RFO-fetched from
// HBM (counters: FETCH 141MB ~= WRITE 139MB, both ~= |S|). New epilogue
// bounces acc through LDS in two 64-row passes and emits contiguous
// float4 stores: 1 KiB/wave-instr = 8 full lines, TCC elides the read.
// ---------------------------------------------------------------------------
__global__ __launch_bounds__(256) void k_sgemm(const f16* __restrict__ comb,
                                               float* __restrict__ Sg, int batch0)
{
    __shared__ char sm[65536];
    const int tid = threadIdx.x, lane = tid & 63, w = tid >> 6;
    const int l15 = lane & 15, quad = lane >> 4;
    const int wm = (w & 1) * 64, wn = (w >> 1) * 64;
    const int ia = wm >> 4, jb = wn >> 4;

    int bx = blockIdx.x, mt = 0;
    while ((mt + 1) * (mt + 2) / 2 <= bx) ++mt;
    const int nt = bx - mt * (mt + 1) / 2;
    const int b = batch0 + blockIdx.y;
    const f16* qa = comb + ((size_t)b * 2048 + mt * 128) * 1024 + 512;
    const f16* qb = comb + ((size_t)b * 2048 + nt * 128) * 1024 + 512;

    floatx4 acc[4][4];
#pragma unroll
    for (int i = 0; i < 4; ++i)
#pragma unroll
        for (int j = 0; j < 4; ++j) acc[i][j] = (floatx4)0.f;

    auto STAGE = [&](int k0, int bsel) {
        f16* At = (f16*)(sm + bsel * 32768);
        f16* Bt = At + 8192;
#pragma unroll
        for (int jr = 0; jr < 4; ++jr) {
            int bi = jr * 4 + w, i2 = bi >> 1, s = bi & 1;
            gload16(qa + (size_t)(i2 * 16 + l15) * 1024 + k0 + s * 32 + quad * 8, At + bi * 512);
            gload16(qb + (size_t)(i2 * 16 + l15) * 1024 + k0 + s * 32 + quad * 8, Bt + bi * 512);
        }
    };

    STAGE(0, 0);
    __syncthreads();
    for (int it = 0; it < 8; ++it) {
        const int cur = it & 1;
        if (it < 7) STAGE((it + 1) * 64, cur ^ 1);
        f16* At = (f16*)(sm + cur * 32768);
        f16* Bt = At + 8192;
#pragma unroll
        for (int s = 0; s < 2; ++s) {
            half8 a[4], bf[4];
#pragma unroll
            for (int i = 0; i < 4; ++i)
                a[i] = *reinterpret_cast<half8*>(At + ((ia + i) * 2 + s) * 512 + lane * 8);
#pragma unroll
            for (int j = 0; j < 4; ++j)
                bf[j] = *reinterpret_cast<half8*>(Bt + ((jb + j) * 2 + s) * 512 + lane * 8);
#pragma unroll
            for (int i = 0; i < 4; ++i)
#pragma unroll
                for (int j = 0; j < 4; ++j)
                    acc[i][j] = MFMA16(a[i], bf[j], acc[i][j]);
        }
        __syncthreads();
    }
    float* St = Sg + ((size_t)blockIdx.y * 136 + bx) * 16384;
    float* cf = (float*)sm;   // [64][128] fp32, 32 KiB (staging bufs dead)
    for (int pass = 0; pass < 2; ++pass) {
        __syncthreads();
        if ((w & 1) == pass) {   // waves holding rows pass*64 .. pass*64+63
#pragma unroll
            for (int i = 0; i < 4; ++i)
#pragma unroll
                for (int j = 0; j < 4; ++j)
#pragma unroll
                    for (int r = 0; r < 4; ++r)
                        cf[(i * 16 + quad * 4 + r) * 128 + wn + j * 16 + l15] = acc[i][j][r];
        }
        __syncthreads();
#pragma unroll
        for (int it = 0; it < 8; ++it) {
            int c = it * 256 + tid, row = c >> 5, c4 = (c & 31) << 2;
            *reinterpret_cast<float4*>(St + (size_t)(pass * 64 + row) * 128 + c4) =
                *reinterpret_cast<float4*>(cf + row * 128 + c4);
        }
    }
}

// ---------------------------------------------------------------------------
// Kernel 3: row softmax, IN-PLACE: reads fp32 S row, writes normalized fp16 P
// into the first half of the same row's storage. Each row is owned by exactly
// one wave (full row registered in sv[] before any store) -> no hazard.
// Single non-restrict pointer (S and P alias).
// ---------------------------------------------------------------------------
__global__ __launch_bounds__(256) void k_softmax(float* Sg)
{
    const int tid = threadIdx.x, lane = tid & 63, w = tid >> 6;
    const int row = blockIdx.x * 4 + w;
    const int gb = blockIdx.y;
    const int mt = row >> 7;
    const size_t tbase = ((size_t)gb * 136 + (size_t)(mt * (mt + 1)) / 2) * 16384;
    const int padlen = (mt + 1) * 128;
    const int r128 = (row & 127) * 128;
    f16* Ph = (f16*)Sg;

    float sv[32];
    float m = -1e38f;
#pragma unroll
    for (int it = 0; it < 32; ++it) {
        int c = it * 64 + lane;
        float p = -1e38f;
        if (c < row) {
            p = Sg[tbase + (size_t)(c >> 7) * 16384 + r128 + (c & 127)];
            m = fmaxf(m, p);
        }
        sv[it] = p;
    }
#pragma unroll
    for (int msk = 32; msk >= 1; msk >>= 1) m = fmaxf(m, __shfl_xor(m, msk));
    float l = 0.f;
#pragma unroll
    for (int it = 0; it < 32; ++it) {
        int c = it * 64 + lane;
        float p = 0.f;
        if (c < row) { p = __expf(sv[it] - m); l += p; }
        sv[it] = p;
    }
#pragma unroll
    for (int msk = 32; msk >= 1; msk >>= 1) l += __shfl_xor(l, msk);
    const float invl = (row > 0) ? 1.f / l : 0.f;
#pragma unroll
    for (int it = 0; it < 32; ++it) {
        int c = it * 64 + lane;
        if (c < padlen)
            Ph[2 * (tbase + (size_t)(c >> 7) * 16384 + r128) + (c & 127)] = (f16)(sv[it] * invl);
    }
}

// ---------------------------------------------------------------------------
// Kernel 4: mix = P @ q (B = qT), fp16 gl_lds GEMM, K = (mt+1)*128.
// P read in-place from the Sg region (fp16 rows at stride 256 halfs).
// Uniform-work pairing (mt=p with 15-p: 34 K-iters/block, 512 blocks) +
// double-buffered 1-barrier pipeline. XCD-pinned via p = id&7.
// ---------------------------------------------------------------------------
__global__ __launch_bounds__(256) void k_pv(const float* Sg,
                                            const f16* __restrict__ qT,
                                            f16* __restrict__ comb, int batch0)
{
    __shared__ char sm[65536];
    const int tid = threadIdx.x, lane = tid & 63, w = tid >> 6;
    const int l15 = lane & 15, quad = lane >> 4;
    const int wm = (w & 1) * 64, wn = (w >> 1) * 64;
    const int ia = wm >> 4, jb = wn >> 4;
    const int id = blockIdx.x;
    const int p = id & 7, nb = (id >> 3) & 3, gb = id >> 5;
    const int b = batch0 + gb;
    const f16* Ph = (const f16*)(Sg + (size_t)gb * 136 * 16384);
    const f16* qTb = qT + ((size_t)b * 512 + nb * 128) * 2048;

    for (int t = 0; t < 2; ++t) {
        const int mt = t ? (15 - p) : p;
        const int tb0 = mt * (mt + 1) / 2;
        const int kit = (mt + 1) * 2;

        floatx4 acc[4][4];
#pragma unroll
        for (int i = 0; i < 4; ++i)
#pragma unroll
            for (int j = 0; j < 4; ++j) acc[i][j] = (floatx4)0.f;

        auto STAGE = [&](int it, int bsel) {
            f16* At = (f16*)(sm + bsel * 32768);
            f16* Bt = At + 8192;
            const int k0 = it * 64;
            const int tt = tb0 + (k0 >> 7), c0 = k0 & 64;
#pragma unroll
            for (int jr = 0; jr < 4; ++jr) {
                int bi = jr * 4 + w, i2 = bi >> 1, s = bi & 1;
                gload16(Ph + 2 * ((size_t)tt * 16384 + (size_t)(i2 * 16 + l15) * 128) + c0 + s * 32 + quad * 8,
                        At + bi * 512);
                gload16(qTb + (size_t)(i2 * 16 + l15) * 2048 + k0 + s * 32 + quad * 8, Bt + bi * 512);
            }
        };

        STAGE(0, 0);
        __syncthreads();   // buf0 ready
        for (int it = 0; it < kit; ++it) {
            const int cur = it & 1;
            if (it + 1 < kit) STAGE(it + 1, cur ^ 1);   // prefetch overlaps compute
            f16* At = (f16*)(sm + cur * 32768);
            f16* Bt = At + 8192;
#pragma unroll
            for (int s = 0; s < 2; ++s) {
                half8 a[4], bf[4];
#pragma unroll
                for (int i = 0; i < 4; ++i)
                    a[i] = *reinterpret_cast<half8*>(At + ((ia + i) * 2 + s) * 512 + lane * 8);
#pragma unroll
                for (int j = 0; j < 4; ++j)
                    bf[j] = *reinterpret_cast<half8*>(Bt + ((jb + j) * 2 + s) * 512 + lane * 8);
#pragma unroll
                for (int i = 0; i < 4; ++i)
#pragma unroll
                    for (int j = 0; j < 4; ++j)
                        acc[i][j] = MFMA16(a[i], bf[j], acc[i][j]);
            }
            __syncthreads();
        }

        // epilogue: ct aliases the staging buffers (all dead past last barrier)
        f16* ct = (f16*)sm;
#pragma unroll
        for (int i = 0; i < 4; ++i)
#pragma unroll
            for (int j = 0; j < 4; ++j)
#pragma unroll
                for (int r = 0; r < 4; ++r)
                    ct[(wm + i * 16 + quad * 4 + r) * 136 + wn + j * 16 + l15] = (f16)acc[i][j][r];
        __syncthreads();
#pragma unroll
        for (int it = 0; it < 8; ++it) {
            int c = it * 256 + tid, r = c >> 4, c8 = (c & 15) << 3;
            *reinterpret_cast<half8*>(comb + ((size_t)b * 2048 + mt * 128 + r) * 1024 + nb * 128 + c8) =
                *reinterpret_cast<half8*>(ct + r * 136 + c8);
        }
        __syncthreads();   // ct reads done before next tile re-stages over it
    }
}

// ---------------------------------------------------------------------------
// Kernel 5: out = comb @ W_out^T (fp16 gl_lds GEMM, fp32 out). K=1024.
// 1D grid 1024, XCD swizzle. Double-buffered 1-barrier K-loop.
// v4: FULL-LINE output stores via two-pass LDS bounce (same RFO fix as
// k_sgemm: out is 134MB of fresh fp32, scattered 4B stores = pure RFO).
// ---------------------------------------------------------------------------
__global__ __launch_bounds__(256) void k_out(const f16* __restrict__ comb,
                                             const f16* __restrict__ Wo16,
                                             float* __restrict__ out)
{
    __shared__ char sm[65536];
    const int tid = threadIdx.x, lane = tid & 63, w = tid >> 6;
    const int l15 = lane & 15, quad = lane >> 4;
    const int id = blockIdx.x, xcd = id & 7, u = id >> 3;
    const int mbase = (xcd * 32 + (u >> 2)) * 128;
    const int nbase = (u & 3) * 128;
    const int wm = (w & 1) * 64, wn = (w >> 1) * 64;
    const int ia = wm >> 4, jb = wn >> 4;

    floatx4 acc[4][4];
#pragma unroll
    for (int i = 0; i < 4; ++i)
#pragma unroll
        for (int j = 0; j < 4; ++j) acc[i][j] = (floatx4)0.f;

    auto STAGE = [&](int k0, int bsel) {
        f16* At = (f16*)(sm + bsel * 32768);
        f16* Bt = At + 8192;
#pragma unroll
        for (int jr = 0; jr < 4; ++jr) {
            int bi = jr * 4 + w, i2 = bi >> 1, s = bi & 1;
            gload16(comb + (size_t)(mbase + i2 * 16 + l15) * 1024 + k0 + s * 32 + quad * 8,
                    At + bi * 512);
            gload16(Wo16 + (size_t)(nbase + i2 * 16 + l15) * 1024 + k0 + s * 32 + quad * 8,
                    Bt + bi * 512);
        }
    };

    STAGE(0, 0);
    __syncthreads();
    for (int it = 0; it < 16; ++it) {
        const int cur = it & 1;
        if (it < 15) STAGE((it + 1) * 64, cur ^ 1);
        f16* At = (f16*)(sm + cur * 32768);
        f16* Bt = At + 8192;
#pragma unroll
        for (int s = 0; s < 2; ++s) {
            half8 a[4], bf[4];
#pragma unroll
            for (int i = 0; i < 4; ++i)
                a[i] = *reinterpret_cast<half8*>(At + ((ia + i) * 2 + s) * 512 + lane * 8);
#pragma unroll
            for (int j = 0; j < 4; ++j)
                bf[j] = *reinterpret_cast<half8*>(Bt + ((jb + j) * 2 + s) * 512 + lane * 8);
#pragma unroll
            for (int i = 0; i < 4; ++i)
#pragma unroll
                for (int j = 0; j < 4; ++j)
                    acc[i][j] = MFMA16(a[i], bf[j], acc[i][j]);
        }
        __syncthreads();
    }
    float* cf = (float*)sm;   // [64][128] fp32, 32 KiB
    for (int pass = 0; pass < 2; ++pass) {
        __syncthreads();
        if ((w & 1) == pass) {
#pragma unroll
            for (int i = 0; i < 4; ++i)
#pragma unroll
                for (int j = 0; j < 4; ++j)
#pragma unroll
                    for (int r = 0; r < 4; ++r)
                        cf[(i * 16 + quad * 4 + r) * 128 + wn + j * 16 + l15] = acc[i][j][r];
        }
        __syncthreads();
#pragma unroll
        for (int it = 0; it < 8; ++it) {
            int c = it * 256 + tid, row = c >> 5, c4 = (c & 31) << 2;
            *reinterpret_cast<float4*>(out + (size_t)(mbase + pass * 64 + row) * 512 + nbase + c4) =
                *reinterpret_cast<float4*>(cf + row * 128 + c4);
        }
    }
}

extern "C" void kernel_launch(void* const* d_in, const int* in_sizes, int n_in,
                              void* d_out, int out_size, void* d_ws, size_t ws_size,
                              hipStream_t stream)
{
    const float* query = (const float*)d_in[0];
    const float* W_in  = (const float*)d_in[1];
    const float* W_out = (const float*)d_in[2];
    float* out = (float*)d_out;

    // ws layout (bytes):
    //   comb fp16 [32768][1024] (mix|q)        @ 0           (67,108,864)
    //   qT   fp16 [16][512][2048]              @ 67,108,864  (33,554,432)
    //   W16  fp16 [Wi 262144 | Wo 524288]      @ 100,663,296 (1,572,864)
    //   X    @ 102,236,160:
    //     q16 fp16 [16*2048*512] (33,554,432)  -- dead after k_qin
    //     Sg fp32 [ng*136*128*128] (aliases q16; P fp16 written in-place)
    const size_t XOFF = 102236160ull;
    f16* comb = (f16*)d_ws;
    f16* qT   = comb + (size_t)32768 * 1024;
    f16* W16  = qT + (size_t)16 * 512 * 2048;
    f16* q16  = (f16*)((char*)d_ws + XOFF);
    const size_t sgb = 136ull * 16384 * 4;   // per-batch Sg bytes (fp32)
    int ng;
    if (ws_size >= XOFF + 16 * sgb)      ng = 16;
    else if (ws_size >= XOFF + 8 * sgb)  ng = 8;
    else                                 ng = 4;
    float* Sg = (float*)((char*)d_ws + XOFF);

    k_cvt<<<17152, 256, 0, stream>>>(query, W_in, W_out, q16, W16);
    k_qin<<<1024, 256, 0, stream>>>(q16, W16, comb, qT);
    for (int g = 0; g < 16 / ng; ++g) {
        k_sgemm<<<dim3(136, ng), 256, 0, stream>>>(comb, Sg, g * ng);
        k_softmax<<<dim3(512, ng), 256, 0, stream>>>(Sg);
        k_pv<<<32 * ng, 256, 0, stream>>>(Sg, qT, comb, g * ng);
    }
    k_out<<<1024, 256, 0, stream>>>(comb, W16 + 262144, out);
}